// Round 1
// baseline (8539.389 us; speedup 1.0000x reference)
//
#include <hip/hip_runtime.h>
#include <math.h>

#define HDIM 128

// ---------------- degree kernels ----------------
__global__ __launch_bounds__(256) void deg_count_k(const int* __restrict__ col,
                                                   float* __restrict__ deg, int E) {
    int e = blockIdx.x * 256 + threadIdx.x;
    if (e < E) atomicAdd(&deg[col[e]], 1.0f);
}

__global__ __launch_bounds__(256) void deg_finish_k(float* __restrict__ dis,
                                                    float* __restrict__ dinv, int N) {
    int n = blockIdx.x * 256 + threadIdx.x;
    if (n < N) {
        double d = (double)dis[n] + 1.0;           // +1 self loop
        dis[n]  = (float)(1.0 / sqrt(d));          // D^-1/2
        dinv[n] = (float)(1.0 / d);                // self-loop norm 1/deg
    }
}

// ---------------- GEMM: xw = relu?(X) @ W ; outi = dinv*xw + b ----------------
// 64 rows x 128 cols per block, BK=32. 256 threads: tx=tid&31 (4 cols), ty=tid>>5 (8 rows).
template<int K, bool RELU>
__global__ __launch_bounds__(256) void gemm_gcn(const float* __restrict__ X,
                                                const float* __restrict__ W,
                                                const float* __restrict__ b,
                                                const float* __restrict__ dinv,
                                                float* __restrict__ xw,
                                                float* __restrict__ outi, int N) {
    __shared__ float xs[32][68];    // [k][row], stride 68 -> 16B-aligned rows, fewer bank conflicts
    __shared__ float ws[32][HDIM];  // [k][col]
    const int tid = threadIdx.x;
    const int tx = tid & 31;        // col group: cols tx*4 .. tx*4+3
    const int ty = tid >> 5;        // row group: rows ty*8 .. ty*8+7
    const int n0 = blockIdx.x * 64;

    float acc[8][4];
#pragma unroll
    for (int r = 0; r < 8; ++r)
#pragma unroll
        for (int c = 0; c < 4; ++c) acc[r][c] = 0.f;

    for (int kc = 0; kc < K; kc += 32) {
        // load 64x32 X tile, transposed into xs[k][row]
#pragma unroll
        for (int i = 0; i < 2; ++i) {
            int f = tid + i * 256;          // float4 id 0..511
            int r = f >> 3;                 // row 0..63
            int kq = f & 7;                 // k quad
            float4 v = make_float4(0.f, 0.f, 0.f, 0.f);
            int n = n0 + r;
            if (n < N) v = *reinterpret_cast<const float4*>(X + (size_t)n * K + kc + kq * 4);
            if (RELU) {
                v.x = fmaxf(v.x, 0.f); v.y = fmaxf(v.y, 0.f);
                v.z = fmaxf(v.z, 0.f); v.w = fmaxf(v.w, 0.f);
            }
            xs[kq * 4 + 0][r] = v.x; xs[kq * 4 + 1][r] = v.y;
            xs[kq * 4 + 2][r] = v.z; xs[kq * 4 + 3][r] = v.w;
        }
        // load 32x128 W tile
#pragma unroll
        for (int i = 0; i < 4; ++i) {
            int f = tid + i * 256;          // float4 id 0..1023
            int kr = f >> 5;
            int c4 = f & 31;
            *reinterpret_cast<float4*>(&ws[kr][c4 * 4]) =
                *reinterpret_cast<const float4*>(W + (size_t)(kc + kr) * HDIM + c4 * 4);
        }
        __syncthreads();
#pragma unroll
        for (int k = 0; k < 32; ++k) {
            float4 xa = *reinterpret_cast<const float4*>(&xs[k][ty * 8]);
            float4 xb = *reinterpret_cast<const float4*>(&xs[k][ty * 8 + 4]);
            float4 w  = *reinterpret_cast<const float4*>(&ws[k][tx * 4]);
            const float xr[8] = {xa.x, xa.y, xa.z, xa.w, xb.x, xb.y, xb.z, xb.w};
            const float wc[4] = {w.x, w.y, w.z, w.w};
#pragma unroll
            for (int r = 0; r < 8; ++r)
#pragma unroll
                for (int c = 0; c < 4; ++c) acc[r][c] += xr[r] * wc[c];
        }
        __syncthreads();
    }
    // epilogue
    float4 bb = *reinterpret_cast<const float4*>(b + tx * 4);
#pragma unroll
    for (int r = 0; r < 8; ++r) {
        int n = n0 + ty * 8 + r;
        if (n >= N) continue;
        float di = dinv[n];
        float4 v = make_float4(acc[r][0], acc[r][1], acc[r][2], acc[r][3]);
        float4 o = make_float4(di * v.x + bb.x, di * v.y + bb.y,
                               di * v.z + bb.z, di * v.w + bb.w);
        size_t base = (size_t)n * HDIM + tx * 4;
        *reinterpret_cast<float4*>(xw + base)   = v;
        *reinterpret_cast<float4*>(outi + base) = o;
    }
}

// ---------------- edge scatter: out[col] += norm * xw[row] ----------------
__global__ __launch_bounds__(256) void scatter_edges(const int* __restrict__ row,
                                                     const int* __restrict__ col,
                                                     const float* __restrict__ dis,
                                                     const float* __restrict__ xw,
                                                     float* __restrict__ out, int E) {
    int idx = blockIdx.x * 256 + threadIdx.x;   // per (edge, h-quad)
    int e = idx >> 5;
    if (e >= E) return;
    int hq = idx & 31;
    int r = row[e], c = col[e];
    float nrm = dis[r] * dis[c];
    float4 v = *reinterpret_cast<const float4*>(xw + (size_t)r * HDIM + hq * 4);
    float* p = out + (size_t)c * HDIM + hq * 4;
    atomicAdd(p + 0, nrm * v.x);
    atomicAdd(p + 1, nrm * v.y);
    atomicAdd(p + 2, nrm * v.z);
    atomicAdd(p + 3, nrm * v.w);
}

// ---------------- pooling ----------------
__global__ __launch_bounds__(256) void pool_sum_k(const float* __restrict__ h,
                                                  const int* __restrict__ batch,
                                                  float* __restrict__ pooled, int N) {
    int idx = blockIdx.x * 256 + threadIdx.x;   // per (node, h-quad)
    int n = idx >> 5;
    if (n >= N) return;
    int hq = idx & 31;
    int g = batch[n];
    float4 v = *reinterpret_cast<const float4*>(h + (size_t)n * HDIM + hq * 4);
    float* p = pooled + (size_t)g * HDIM + hq * 4;
    atomicAdd(p + 0, v.x);
    atomicAdd(p + 1, v.y);
    atomicAdd(p + 2, v.z);
    atomicAdd(p + 3, v.w);
}

__global__ __launch_bounds__(256) void count_nodes_k(const int* __restrict__ batch,
                                                     float* __restrict__ cnt, int N) {
    int n = blockIdx.x * 256 + threadIdx.x;
    if (n < N) atomicAdd(&cnt[batch[n]], 1.0f);
}

// ---------------- final: out[g] = mean(pooled[g]) . Wlin + blin ----------------
__global__ __launch_bounds__(256) void final_dot_k(const float* __restrict__ pooled,
                                                   const float* __restrict__ cnt,
                                                   const float* __restrict__ Wlin,
                                                   const float* __restrict__ blin,
                                                   float* __restrict__ out, int G) {
    int w = threadIdx.x >> 6;
    int lane = threadIdx.x & 63;
    int g = blockIdx.x * 4 + w;
    if (g >= G) return;
    float s = pooled[(size_t)g * HDIM + lane] * Wlin[lane] +
              pooled[(size_t)g * HDIM + lane + 64] * Wlin[lane + 64];
#pragma unroll
    for (int off = 32; off > 0; off >>= 1) s += __shfl_down(s, off);
    if (lane == 0) out[g] = s / fmaxf(cnt[g], 1.0f) + blin[0];
}

extern "C" void kernel_launch(void* const* d_in, const int* in_sizes, int n_in,
                              void* d_out, int out_size, void* d_ws, size_t ws_size,
                              hipStream_t stream) {
    const float* x    = (const float*)d_in[0];
    const float* W1   = (const float*)d_in[1];
    const float* b1   = (const float*)d_in[2];
    const float* W2   = (const float*)d_in[3];
    const float* b2   = (const float*)d_in[4];
    const float* W3   = (const float*)d_in[5];
    const float* b3   = (const float*)d_in[6];
    const float* Wlin = (const float*)d_in[7];
    const float* blin = (const float*)d_in[8];
    const int* ei     = (const int*)d_in[9];
    const int* batch  = (const int*)d_in[10];

    const int N = in_sizes[10];
    const int E = in_sizes[9] / 2;
    const int G = out_size;
    const int NH = N * HDIM;

    const int* row = ei;
    const int* col = ei + E;

    float* ws = (float*)d_ws;
    float* dis    = ws;                      // [N]  D^-1/2
    float* dinv   = ws + N;                  // [N]  1/deg
    float* xw     = ws + 2 * (size_t)N;           // [N,H]
    float* bufA   = xw + (size_t)NH;              // [N,H]
    float* bufB   = bufA + (size_t)NH;            // [N,H]
    float* pooled = bufB + (size_t)NH;            // [G,H]
    float* cnt    = pooled + (size_t)G * HDIM;    // [G]

    float* outf = (float*)d_out;

    // degrees
    hipMemsetAsync(dis, 0, (size_t)N * sizeof(float), stream);
    deg_count_k<<<(E + 255) / 256, 256, 0, stream>>>(col, dis, E);
    deg_finish_k<<<(N + 255) / 256, 256, 0, stream>>>(dis, dinv, N);

    const int gemm_grid = (N + 63) / 64;
    const int scat_grid = (E * 32 + 255) / 256;

    // layer 1: x(K=32) -> bufA
    gemm_gcn<32, false><<<gemm_grid, 256, 0, stream>>>(x, W1, b1, dinv, xw, bufA, N);
    scatter_edges<<<scat_grid, 256, 0, stream>>>(row, col, dis, xw, bufA, E);
    // layer 2: relu(bufA)(K=128) -> bufB
    gemm_gcn<128, true><<<gemm_grid, 256, 0, stream>>>(bufA, W2, b2, dinv, xw, bufB, N);
    scatter_edges<<<scat_grid, 256, 0, stream>>>(row, col, dis, xw, bufB, E);
    // layer 3: relu(bufB)(K=128) -> bufA
    gemm_gcn<128, true><<<gemm_grid, 256, 0, stream>>>(bufB, W3, b3, dinv, xw, bufA, N);
    scatter_edges<<<scat_grid, 256, 0, stream>>>(row, col, dis, xw, bufA, E);

    // pooling
    hipMemsetAsync(pooled, 0, ((size_t)G * HDIM + G) * sizeof(float), stream);
    pool_sum_k<<<(N * 32 + 255) / 256, 256, 0, stream>>>(bufA, batch, pooled, N);
    count_nodes_k<<<(N + 255) / 256, 256, 0, stream>>>(batch, cnt, N);

    // final linear
    final_dot_k<<<(G + 3) / 4, 256, 0, stream>>>(pooled, cnt, Wlin, blin, outf, G);
}

// Round 2
// 848.761 us; speedup vs baseline: 10.0610x; 10.0610x over previous
//
#include <hip/hip_runtime.h>
#include <math.h>

#define HDIM 128

// ---------------- degree histogram (int) ----------------
__global__ __launch_bounds__(256) void deg_hist_k(const int* __restrict__ col,
                                                  int* __restrict__ deg, int E) {
    int e = blockIdx.x * 256 + threadIdx.x;
    if (e < E) atomicAdd(&deg[col[e]], 1);
}

__global__ __launch_bounds__(256) void deg_finish_k(const int* __restrict__ deg,
                                                    float* __restrict__ dis,
                                                    float* __restrict__ dinv, int N) {
    int n = blockIdx.x * 256 + threadIdx.x;
    if (n < N) {
        double d = (double)deg[n] + 1.0;           // +1 self loop
        dis[n]  = (float)(1.0 / sqrt(d));          // D^-1/2
        dinv[n] = (float)(1.0 / d);                // self-loop norm 1/deg
    }
}

// ---------------- single-block exclusive scan: row_ptr from deg ----------------
__global__ __launch_bounds__(1024) void scan_k(const int* __restrict__ deg,
                                               int* __restrict__ row_ptr, int N) {
    __shared__ int sums[1024];
    const int t = threadIdx.x;
    const int chunk = (N + 1023) >> 10;
    const int s0 = t * chunk;
    const int s1 = min(s0 + chunk, N);
    int s = 0;
    for (int i = s0; i < s1; ++i) s += deg[i];
    sums[t] = s;
    __syncthreads();
    // inclusive Hillis-Steele scan
    for (int off = 1; off < 1024; off <<= 1) {
        int v = (t >= off) ? sums[t - off] : 0;
        __syncthreads();
        sums[t] += v;
        __syncthreads();
    }
    int run = (t == 0) ? 0 : sums[t - 1];
    for (int i = s0; i < s1; ++i) { row_ptr[i] = run; run += deg[i]; }
    if (t == 1023) row_ptr[N] = run;   // == E (tail threads have empty chunks)
}

// ---------------- CSR fill (counting sort by destination) ----------------
__global__ __launch_bounds__(256) void csr_fill_k(const int* __restrict__ row,
                                                  const int* __restrict__ col,
                                                  const float* __restrict__ dis,
                                                  const int* __restrict__ row_ptr,
                                                  int* __restrict__ cursor,
                                                  int2* __restrict__ csr, int E) {
    int e = blockIdx.x * 256 + threadIdx.x;
    if (e >= E) return;
    int r = row[e], c = col[e];
    int pos = atomicAdd(&cursor[c], 1);
    float nrm = dis[r] * dis[c];
    csr[row_ptr[c] + pos] = make_int2(r, __float_as_int(nrm));
}

// ---------------- GEMM: xw = relu?(X) @ W ----------------
// 64 rows x 128 cols per block, BK=32. 256 threads: tx=tid&31 (4 cols), ty=tid>>5 (8 rows).
template<int K, bool RELU>
__global__ __launch_bounds__(256) void gemm_gcn(const float* __restrict__ X,
                                                const float* __restrict__ W,
                                                float* __restrict__ xw, int N) {
    __shared__ float xs[32][68];
    __shared__ float ws[32][HDIM];
    const int tid = threadIdx.x;
    const int tx = tid & 31;
    const int ty = tid >> 5;
    const int n0 = blockIdx.x * 64;

    float acc[8][4];
#pragma unroll
    for (int r = 0; r < 8; ++r)
#pragma unroll
        for (int c = 0; c < 4; ++c) acc[r][c] = 0.f;

    for (int kc = 0; kc < K; kc += 32) {
#pragma unroll
        for (int i = 0; i < 2; ++i) {
            int f = tid + i * 256;
            int r = f >> 3;
            int kq = f & 7;
            float4 v = make_float4(0.f, 0.f, 0.f, 0.f);
            int n = n0 + r;
            if (n < N) v = *reinterpret_cast<const float4*>(X + (size_t)n * K + kc + kq * 4);
            if (RELU) {
                v.x = fmaxf(v.x, 0.f); v.y = fmaxf(v.y, 0.f);
                v.z = fmaxf(v.z, 0.f); v.w = fmaxf(v.w, 0.f);
            }
            xs[kq * 4 + 0][r] = v.x; xs[kq * 4 + 1][r] = v.y;
            xs[kq * 4 + 2][r] = v.z; xs[kq * 4 + 3][r] = v.w;
        }
#pragma unroll
        for (int i = 0; i < 4; ++i) {
            int f = tid + i * 256;
            int kr = f >> 5;
            int c4 = f & 31;
            *reinterpret_cast<float4*>(&ws[kr][c4 * 4]) =
                *reinterpret_cast<const float4*>(W + (size_t)(kc + kr) * HDIM + c4 * 4);
        }
        __syncthreads();
#pragma unroll
        for (int k = 0; k < 32; ++k) {
            float4 xa = *reinterpret_cast<const float4*>(&xs[k][ty * 8]);
            float4 xb = *reinterpret_cast<const float4*>(&xs[k][ty * 8 + 4]);
            float4 w  = *reinterpret_cast<const float4*>(&ws[k][tx * 4]);
            const float xr[8] = {xa.x, xa.y, xa.z, xa.w, xb.x, xb.y, xb.z, xb.w};
            const float wc[4] = {w.x, w.y, w.z, w.w};
#pragma unroll
            for (int r = 0; r < 8; ++r)
#pragma unroll
                for (int c = 0; c < 4; ++c) acc[r][c] += xr[r] * wc[c];
        }
        __syncthreads();
    }
#pragma unroll
    for (int r = 0; r < 8; ++r) {
        int n = n0 + ty * 8 + r;
        if (n >= N) continue;
        *reinterpret_cast<float4*>(xw + (size_t)n * HDIM + tx * 4) =
            make_float4(acc[r][0], acc[r][1], acc[r][2], acc[r][3]);
    }
}

// ---------------- CSR gather: out[c] = dinv[c]*xw[c] + b + sum nrm*xw[r] ----------------
__global__ __launch_bounds__(256) void gather_k(const int* __restrict__ row_ptr,
                                                const int2* __restrict__ csr,
                                                const float* __restrict__ dinv,
                                                const float* __restrict__ b,
                                                const float* __restrict__ xw,
                                                float* __restrict__ out, int N) {
    int idx = blockIdx.x * 256 + threadIdx.x;   // per (node, h-quad)
    int c = idx >> 5;
    if (c >= N) return;
    int hq = idx & 31;
    int j0 = row_ptr[c], j1 = row_ptr[c + 1];
    float4 xc = *reinterpret_cast<const float4*>(xw + (size_t)c * HDIM + hq * 4);
    float di = dinv[c];
    float4 bb = *reinterpret_cast<const float4*>(b + hq * 4);
    float4 acc = make_float4(di * xc.x + bb.x, di * xc.y + bb.y,
                             di * xc.z + bb.z, di * xc.w + bb.w);
    for (int j = j0; j < j1; ++j) {
        int2 en = csr[j];
        float nrm = __int_as_float(en.y);
        float4 v = *reinterpret_cast<const float4*>(xw + (size_t)en.x * HDIM + hq * 4);
        acc.x += nrm * v.x; acc.y += nrm * v.y;
        acc.z += nrm * v.z; acc.w += nrm * v.w;
    }
    *reinterpret_cast<float4*>(out + (size_t)c * HDIM + hq * 4) = acc;
}

// ---------------- graph start offsets (batch is sorted) ----------------
__global__ __launch_bounds__(256) void gstart_k(const int* __restrict__ batch,
                                                int* __restrict__ start, int N, int G) {
    int n = blockIdx.x * 256 + threadIdx.x;
    if (n > N) return;
    if (n < N) {
        int b = batch[n];
        int prev = (n == 0) ? -1 : batch[n - 1];
        for (int g = prev + 1; g <= b; ++g) start[g] = n;
    } else {
        int prev = batch[N - 1];
        for (int g = prev + 1; g <= G; ++g) start[g] = N;
    }
}

// ---------------- fused mean-pool + final linear ----------------
__global__ __launch_bounds__(256) void final_pool_k(const float* __restrict__ h,
                                                    const int* __restrict__ start,
                                                    const float* __restrict__ Wlin,
                                                    const float* __restrict__ blin,
                                                    float* __restrict__ out, int G) {
    int g = blockIdx.x * 4 + (threadIdx.x >> 6);
    int lane = threadIdx.x & 63;
    if (g >= G) return;
    int s = start[g], e = start[g + 1];
    float w0 = Wlin[lane], w1 = Wlin[lane + 64];
    float acc = 0.f;
    for (int n = s; n < e; ++n) {
        const float* p = h + (size_t)n * HDIM;
        acc += p[lane] * w0 + p[lane + 64] * w1;
    }
#pragma unroll
    for (int off = 32; off > 0; off >>= 1) acc += __shfl_down(acc, off);
    if (lane == 0) out[g] = acc / fmaxf((float)(e - s), 1.0f) + blin[0];
}

extern "C" void kernel_launch(void* const* d_in, const int* in_sizes, int n_in,
                              void* d_out, int out_size, void* d_ws, size_t ws_size,
                              hipStream_t stream) {
    const float* x    = (const float*)d_in[0];
    const float* W1   = (const float*)d_in[1];
    const float* b1   = (const float*)d_in[2];
    const float* W2   = (const float*)d_in[3];
    const float* b2   = (const float*)d_in[4];
    const float* W3   = (const float*)d_in[5];
    const float* b3   = (const float*)d_in[6];
    const float* Wlin = (const float*)d_in[7];
    const float* blin = (const float*)d_in[8];
    const int* ei     = (const int*)d_in[9];
    const int* batch  = (const int*)d_in[10];

    const int N = in_sizes[10];
    const int E = in_sizes[9] / 2;
    const int G = out_size;
    const size_t NH = (size_t)N * HDIM;

    const int* row = ei;
    const int* col = ei + E;

    // workspace layout (csr first for 8B alignment)
    int2* csr     = (int2*)d_ws;                 // [E]
    float* xw     = (float*)(csr + E);           // [N,H]
    float* bufA   = xw + NH;                     // [N,H]
    float* dis    = bufA + NH;                   // [N]
    float* dinv   = dis + N;                     // [N]
    int* deg_i    = (int*)(dinv + N);            // [N]
    int* row_ptr  = deg_i + N;                   // [N+1]
    int* cursor   = row_ptr + N + 1;             // [N]
    int* gstart   = cursor + N;                  // [G+1]

    float* outf = (float*)d_out;

    // ---- CSR build ----
    hipMemsetAsync(deg_i, 0, (size_t)N * sizeof(int), stream);
    hipMemsetAsync(cursor, 0, (size_t)N * sizeof(int), stream);
    deg_hist_k<<<(E + 255) / 256, 256, 0, stream>>>(col, deg_i, E);
    deg_finish_k<<<(N + 255) / 256, 256, 0, stream>>>(deg_i, dis, dinv, N);
    scan_k<<<1, 1024, 0, stream>>>(deg_i, row_ptr, N);
    csr_fill_k<<<(E + 255) / 256, 256, 0, stream>>>(row, col, dis, row_ptr, cursor, csr, E);
    gstart_k<<<(N + 256) / 256, 256, 0, stream>>>(batch, gstart, N, G);

    const int gemm_grid = (N + 63) / 64;
    const int gath_grid = (N * 32 + 255) / 256;

    // layer 1: x(K=32) -> xw; gather -> bufA
    gemm_gcn<32, false><<<gemm_grid, 256, 0, stream>>>(x, W1, xw, N);
    gather_k<<<gath_grid, 256, 0, stream>>>(row_ptr, csr, dinv, b1, xw, bufA, N);
    // layer 2: relu(bufA)(K=128) -> xw; gather -> bufA
    gemm_gcn<128, true><<<gemm_grid, 256, 0, stream>>>(bufA, W2, xw, N);
    gather_k<<<gath_grid, 256, 0, stream>>>(row_ptr, csr, dinv, b2, xw, bufA, N);
    // layer 3: relu(bufA)(K=128) -> xw; gather -> bufA
    gemm_gcn<128, true><<<gemm_grid, 256, 0, stream>>>(bufA, W3, xw, N);
    gather_k<<<gath_grid, 256, 0, stream>>>(row_ptr, csr, dinv, b3, xw, bufA, N);

    // fused mean-pool + linear
    final_pool_k<<<(G + 3) / 4, 256, 0, stream>>>(bufA, gstart, Wlin, blin, outf, G);
}

// Round 3
// 698.114 us; speedup vs baseline: 12.2321x; 1.2158x over previous
//
#include <hip/hip_runtime.h>
#include <math.h>

#define HDIM 128

// ---------------- degree histogram (int) ----------------
__global__ __launch_bounds__(256) void deg_hist_k(const int* __restrict__ col,
                                                  int* __restrict__ deg, int E) {
    int e = blockIdx.x * 256 + threadIdx.x;
    if (e < E) atomicAdd(&deg[col[e]], 1);
}

__global__ __launch_bounds__(256) void deg_finish_k(const int* __restrict__ deg,
                                                    float* __restrict__ dis,
                                                    float* __restrict__ dinv, int N) {
    int n = blockIdx.x * 256 + threadIdx.x;
    if (n < N) {
        double d = (double)deg[n] + 1.0;           // +1 self loop
        dis[n]  = (float)(1.0 / sqrt(d));          // D^-1/2
        dinv[n] = (float)(1.0 / d);                // self-loop norm 1/deg
    }
}

// ---------------- hierarchical exclusive scan (3 kernels) ----------------
__global__ __launch_bounds__(256) void scan1_k(const int* __restrict__ deg,
                                               int* __restrict__ incl,
                                               int* __restrict__ partial, int N) {
    int i = blockIdx.x * 256 + threadIdx.x;
    int lane = threadIdx.x & 63;
    int wid = threadIdx.x >> 6;
    int s = (i < N) ? deg[i] : 0;
#pragma unroll
    for (int off = 1; off < 64; off <<= 1) {
        int t = __shfl_up(s, off);
        if (lane >= off) s += t;
    }
    __shared__ int wsum[4];
    if (lane == 63) wsum[wid] = s;
    __syncthreads();
    if (threadIdx.x == 0) {
        int run = 0;
#pragma unroll
        for (int w = 0; w < 4; ++w) { int t = wsum[w]; wsum[w] = run; run += t; }
    }
    __syncthreads();
    s += wsum[wid];
    if (i < N) incl[i] = s;
    if (threadIdx.x == 255) partial[blockIdx.x] = s;   // block total (pad elems are 0)
}

__global__ __launch_bounds__(512) void scan2_k(int* __restrict__ partial, int NB) {
    __shared__ int sm[512];
    int t = threadIdx.x;
    sm[t] = (t < NB) ? partial[t] : 0;
    __syncthreads();
    for (int off = 1; off < 512; off <<= 1) {
        int v = (t >= off) ? sm[t - off] : 0;
        __syncthreads();
        sm[t] += v;
        __syncthreads();
    }
    if (t < NB) partial[t] = (t == 0) ? 0 : sm[t - 1];
}

__global__ __launch_bounds__(256) void scan3_k(const int* __restrict__ deg,
                                               const int* __restrict__ incl,
                                               const int* __restrict__ partial,
                                               int* __restrict__ row_ptr, int N) {
    int i = blockIdx.x * 256 + threadIdx.x;
    if (i < N) {
        int off = partial[blockIdx.x];
        row_ptr[i] = incl[i] - deg[i] + off;
        if (i == N - 1) row_ptr[N] = incl[i] + off;
    }
}

// ---------------- CSR fill (counting sort by destination) ----------------
__global__ __launch_bounds__(256) void csr_fill_k(const int* __restrict__ row,
                                                  const int* __restrict__ col,
                                                  const float* __restrict__ dis,
                                                  const int* __restrict__ row_ptr,
                                                  int* __restrict__ cursor,
                                                  int2* __restrict__ csr, int E) {
    int e = blockIdx.x * 256 + threadIdx.x;
    if (e >= E) return;
    int r = row[e], c = col[e];
    int pos = atomicAdd(&cursor[c], 1);
    float nrm = dis[r] * dis[c];
    csr[row_ptr[c] + pos] = make_int2(r, __float_as_int(nrm));
}

// ---------------- GEMM: xw = relu?(X) @ W ----------------
template<int K, bool RELU>
__global__ __launch_bounds__(256) void gemm_gcn(const float* __restrict__ X,
                                                const float* __restrict__ W,
                                                float* __restrict__ xw, int N) {
    __shared__ float xs[32][68];
    __shared__ float ws[32][HDIM];
    const int tid = threadIdx.x;
    const int tx = tid & 31;
    const int ty = tid >> 5;
    const int n0 = blockIdx.x * 64;

    float acc[8][4];
#pragma unroll
    for (int r = 0; r < 8; ++r)
#pragma unroll
        for (int c = 0; c < 4; ++c) acc[r][c] = 0.f;

    for (int kc = 0; kc < K; kc += 32) {
#pragma unroll
        for (int i = 0; i < 2; ++i) {
            int f = tid + i * 256;
            int r = f >> 3;
            int kq = f & 7;
            float4 v = make_float4(0.f, 0.f, 0.f, 0.f);
            int n = n0 + r;
            if (n < N) v = *reinterpret_cast<const float4*>(X + (size_t)n * K + kc + kq * 4);
            if (RELU) {
                v.x = fmaxf(v.x, 0.f); v.y = fmaxf(v.y, 0.f);
                v.z = fmaxf(v.z, 0.f); v.w = fmaxf(v.w, 0.f);
            }
            xs[kq * 4 + 0][r] = v.x; xs[kq * 4 + 1][r] = v.y;
            xs[kq * 4 + 2][r] = v.z; xs[kq * 4 + 3][r] = v.w;
        }
#pragma unroll
        for (int i = 0; i < 4; ++i) {
            int f = tid + i * 256;
            int kr = f >> 5;
            int c4 = f & 31;
            *reinterpret_cast<float4*>(&ws[kr][c4 * 4]) =
                *reinterpret_cast<const float4*>(W + (size_t)(kc + kr) * HDIM + c4 * 4);
        }
        __syncthreads();
#pragma unroll
        for (int k = 0; k < 32; ++k) {
            float4 xa = *reinterpret_cast<const float4*>(&xs[k][ty * 8]);
            float4 xb = *reinterpret_cast<const float4*>(&xs[k][ty * 8 + 4]);
            float4 w  = *reinterpret_cast<const float4*>(&ws[k][tx * 4]);
            const float xr[8] = {xa.x, xa.y, xa.z, xa.w, xb.x, xb.y, xb.z, xb.w};
            const float wc[4] = {w.x, w.y, w.z, w.w};
#pragma unroll
            for (int r = 0; r < 8; ++r)
#pragma unroll
                for (int c = 0; c < 4; ++c) acc[r][c] += xr[r] * wc[c];
        }
        __syncthreads();
    }
#pragma unroll
    for (int r = 0; r < 8; ++r) {
        int n = n0 + ty * 8 + r;
        if (n >= N) continue;
        *reinterpret_cast<float4*>(xw + (size_t)n * HDIM + tx * 4) =
            make_float4(acc[r][0], acc[r][1], acc[r][2], acc[r][3]);
    }
}

// ---------------- CSR gather: out[c] = dinv[c]*xw[c] + b + sum nrm*xw[r] ----------------
__global__ __launch_bounds__(256) void gather_k(const int* __restrict__ row_ptr,
                                                const int2* __restrict__ csr,
                                                const float* __restrict__ dinv,
                                                const float* __restrict__ b,
                                                const float* __restrict__ xw,
                                                float* __restrict__ out, int N) {
    int idx = blockIdx.x * 256 + threadIdx.x;   // per (node, h-quad)
    int c = idx >> 5;
    if (c >= N) return;
    int hq = idx & 31;
    int j0 = row_ptr[c], j1 = row_ptr[c + 1];
    float4 xc = *reinterpret_cast<const float4*>(xw + (size_t)c * HDIM + hq * 4);
    float di = dinv[c];
    float4 bb = *reinterpret_cast<const float4*>(b + hq * 4);
    float4 acc = make_float4(di * xc.x + bb.x, di * xc.y + bb.y,
                             di * xc.z + bb.z, di * xc.w + bb.w);
    for (int j = j0; j < j1; ++j) {
        int2 en = csr[j];
        float nrm = __int_as_float(en.y);
        float4 v = *reinterpret_cast<const float4*>(xw + (size_t)en.x * HDIM + hq * 4);
        acc.x += nrm * v.x; acc.y += nrm * v.y;
        acc.z += nrm * v.z; acc.w += nrm * v.w;
    }
    *reinterpret_cast<float4*>(out + (size_t)c * HDIM + hq * 4) = acc;
}

// ---------------- graph start offsets (batch is sorted) ----------------
__global__ __launch_bounds__(256) void gstart_k(const int* __restrict__ batch,
                                                int* __restrict__ start, int N, int G) {
    int n = blockIdx.x * 256 + threadIdx.x;
    if (n > N) return;
    if (n < N) {
        int b = batch[n];
        int prev = (n == 0) ? -1 : batch[n - 1];
        for (int g = prev + 1; g <= b; ++g) start[g] = n;
    } else {
        int prev = batch[N - 1];
        for (int g = prev + 1; g <= G; ++g) start[g] = N;
    }
}

// ---------------- fused mean-pool + final linear ----------------
__global__ __launch_bounds__(256) void final_pool_k(const float* __restrict__ h,
                                                    const int* __restrict__ start,
                                                    const float* __restrict__ Wlin,
                                                    const float* __restrict__ blin,
                                                    float* __restrict__ out, int G) {
    int g = blockIdx.x * 4 + (threadIdx.x >> 6);
    int lane = threadIdx.x & 63;
    if (g >= G) return;
    int s = start[g], e = start[g + 1];
    float w0 = Wlin[lane], w1 = Wlin[lane + 64];
    float acc = 0.f;
    for (int n = s; n < e; ++n) {
        const float* p = h + (size_t)n * HDIM;
        acc += p[lane] * w0 + p[lane + 64] * w1;
    }
#pragma unroll
    for (int off = 32; off > 0; off >>= 1) acc += __shfl_down(acc, off);
    if (lane == 0) out[g] = acc / fmaxf((float)(e - s), 1.0f) + blin[0];
}

extern "C" void kernel_launch(void* const* d_in, const int* in_sizes, int n_in,
                              void* d_out, int out_size, void* d_ws, size_t ws_size,
                              hipStream_t stream) {
    const float* x    = (const float*)d_in[0];
    const float* W1   = (const float*)d_in[1];
    const float* b1   = (const float*)d_in[2];
    const float* W2   = (const float*)d_in[3];
    const float* b2   = (const float*)d_in[4];
    const float* W3   = (const float*)d_in[5];
    const float* b3   = (const float*)d_in[6];
    const float* Wlin = (const float*)d_in[7];
    const float* blin = (const float*)d_in[8];
    const int* ei     = (const int*)d_in[9];
    const int* batch  = (const int*)d_in[10];

    const int N = in_sizes[10];
    const int E = in_sizes[9] / 2;
    const int G = out_size;
    const size_t NH = (size_t)N * HDIM;
    const int NB = (N + 255) / 256;               // scan blocks (<=512)

    const int* row = ei;
    const int* col = ei + E;

    // workspace layout (csr first for 8B alignment)
    int2* csr     = (int2*)d_ws;                 // [E]
    float* xw     = (float*)(csr + E);           // [N,H]
    float* bufA   = xw + NH;                     // [N,H]
    float* dis    = bufA + NH;                   // [N]
    float* dinv   = dis + N;                     // [N]
    int* deg_i    = (int*)(dinv + N);            // [N]
    int* row_ptr  = deg_i + N;                   // [N+1]
    int* cursor   = row_ptr + N + 1;             // [N]
    int* gstart   = cursor + N;                  // [G+1]
    int* incl     = gstart + G + 1;              // [N]
    int* partial  = incl + N;                    // [NB]

    float* outf = (float*)d_out;

    // ---- CSR build ----
    hipMemsetAsync(deg_i, 0, (size_t)N * sizeof(int), stream);
    hipMemsetAsync(cursor, 0, (size_t)N * sizeof(int), stream);
    deg_hist_k<<<(E + 255) / 256, 256, 0, stream>>>(col, deg_i, E);
    deg_finish_k<<<(N + 255) / 256, 256, 0, stream>>>(deg_i, dis, dinv, N);
    scan1_k<<<NB, 256, 0, stream>>>(deg_i, incl, partial, N);
    scan2_k<<<1, 512, 0, stream>>>(partial, NB);
    scan3_k<<<NB, 256, 0, stream>>>(deg_i, incl, partial, row_ptr, N);
    csr_fill_k<<<(E + 255) / 256, 256, 0, stream>>>(row, col, dis, row_ptr, cursor, csr, E);
    gstart_k<<<(N + 256) / 256, 256, 0, stream>>>(batch, gstart, N, G);

    const int gemm_grid = (N + 63) / 64;
    const int gath_grid = (N * 32 + 255) / 256;

    // layer 1: x(K=32) -> xw; gather -> bufA
    gemm_gcn<32, false><<<gemm_grid, 256, 0, stream>>>(x, W1, xw, N);
    gather_k<<<gath_grid, 256, 0, stream>>>(row_ptr, csr, dinv, b1, xw, bufA, N);
    // layer 2: relu(bufA)(K=128) -> xw; gather -> bufA
    gemm_gcn<128, true><<<gemm_grid, 256, 0, stream>>>(bufA, W2, xw, N);
    gather_k<<<gath_grid, 256, 0, stream>>>(row_ptr, csr, dinv, b2, xw, bufA, N);
    // layer 3: relu(bufA)(K=128) -> xw; gather -> bufA
    gemm_gcn<128, true><<<gemm_grid, 256, 0, stream>>>(bufA, W3, xw, N);
    gather_k<<<gath_grid, 256, 0, stream>>>(row_ptr, csr, dinv, b3, xw, bufA, N);

    // fused mean-pool + linear
    final_pool_k<<<(G + 3) / 4, 256, 0, stream>>>(bufA, gstart, Wlin, blin, outf, G);
}

// Round 4
// 589.254 us; speedup vs baseline: 14.4919x; 1.1847x over previous
//
#include <hip/hip_runtime.h>
#include <math.h>

#define HDIM 128

// ---------------- degree histogram (int) ----------------
__global__ __launch_bounds__(256) void deg_hist_k(const int* __restrict__ col,
                                                  int* __restrict__ deg, int E) {
    int e = blockIdx.x * 256 + threadIdx.x;
    if (e < E) atomicAdd(&deg[col[e]], 1);
}

__global__ __launch_bounds__(256) void deg_finish_k(const int* __restrict__ deg,
                                                    float* __restrict__ dis,
                                                    float* __restrict__ dinv, int N) {
    int n = blockIdx.x * 256 + threadIdx.x;
    if (n < N) {
        double d = (double)deg[n] + 1.0;           // +1 self loop
        dis[n]  = (float)(1.0 / sqrt(d));          // D^-1/2
        dinv[n] = (float)(1.0 / d);                // self-loop norm 1/deg
    }
}

// ---------------- hierarchical exclusive scan (3 kernels) ----------------
__global__ __launch_bounds__(256) void scan1_k(const int* __restrict__ deg,
                                               int* __restrict__ incl,
                                               int* __restrict__ partial, int N) {
    int i = blockIdx.x * 256 + threadIdx.x;
    int lane = threadIdx.x & 63;
    int wid = threadIdx.x >> 6;
    int s = (i < N) ? deg[i] : 0;
#pragma unroll
    for (int off = 1; off < 64; off <<= 1) {
        int t = __shfl_up(s, off);
        if (lane >= off) s += t;
    }
    __shared__ int wsum[4];
    if (lane == 63) wsum[wid] = s;
    __syncthreads();
    if (threadIdx.x == 0) {
        int run = 0;
#pragma unroll
        for (int w = 0; w < 4; ++w) { int t = wsum[w]; wsum[w] = run; run += t; }
    }
    __syncthreads();
    s += wsum[wid];
    if (i < N) incl[i] = s;
    if (threadIdx.x == 255) partial[blockIdx.x] = s;
}

__global__ __launch_bounds__(512) void scan2_k(int* __restrict__ partial, int NB) {
    __shared__ int sm[512];
    int t = threadIdx.x;
    sm[t] = (t < NB) ? partial[t] : 0;
    __syncthreads();
    for (int off = 1; off < 512; off <<= 1) {
        int v = (t >= off) ? sm[t - off] : 0;
        __syncthreads();
        sm[t] += v;
        __syncthreads();
    }
    if (t < NB) partial[t] = (t == 0) ? 0 : sm[t - 1];
}

__global__ __launch_bounds__(256) void scan3_k(const int* __restrict__ deg,
                                               const int* __restrict__ incl,
                                               const int* __restrict__ partial,
                                               int* __restrict__ row_ptr, int N) {
    int i = blockIdx.x * 256 + threadIdx.x;
    if (i < N) {
        int off = partial[blockIdx.x];
        row_ptr[i] = incl[i] - deg[i] + off;
        if (i == N - 1) row_ptr[N] = incl[i] + off;
    }
}

// ---------------- CSR fill (counting sort by destination) ----------------
__global__ __launch_bounds__(256) void csr_fill_k(const int* __restrict__ row,
                                                  const int* __restrict__ col,
                                                  const float* __restrict__ dis,
                                                  const int* __restrict__ row_ptr,
                                                  int* __restrict__ cursor,
                                                  int2* __restrict__ csr, int E) {
    int e = blockIdx.x * 256 + threadIdx.x;
    if (e >= E) return;
    int r = row[e], c = col[e];
    int pos = atomicAdd(&cursor[c], 1);
    float nrm = dis[r] * dis[c];
    csr[row_ptr[c] + pos] = make_int2(r, __float_as_int(nrm));
}

// ---------------- GEMM: out = relu?(X) @ W [+ bias] ----------------
template<int K, bool RELU, bool BIAS>
__global__ __launch_bounds__(256) void gemm_gcn(const float* __restrict__ X,
                                                const float* __restrict__ W,
                                                const float* __restrict__ b,
                                                float* __restrict__ out, int N) {
    __shared__ float xs[32][68];
    __shared__ float ws[32][HDIM];
    const int tid = threadIdx.x;
    const int tx = tid & 31;
    const int ty = tid >> 5;
    const int n0 = blockIdx.x * 64;

    float acc[8][4];
#pragma unroll
    for (int r = 0; r < 8; ++r)
#pragma unroll
        for (int c = 0; c < 4; ++c) acc[r][c] = 0.f;

    for (int kc = 0; kc < K; kc += 32) {
#pragma unroll
        for (int i = 0; i < 2; ++i) {
            int f = tid + i * 256;
            int r = f >> 3;
            int kq = f & 7;
            float4 v = make_float4(0.f, 0.f, 0.f, 0.f);
            int n = n0 + r;
            if (n < N) v = *reinterpret_cast<const float4*>(X + (size_t)n * K + kc + kq * 4);
            if (RELU) {
                v.x = fmaxf(v.x, 0.f); v.y = fmaxf(v.y, 0.f);
                v.z = fmaxf(v.z, 0.f); v.w = fmaxf(v.w, 0.f);
            }
            xs[kq * 4 + 0][r] = v.x; xs[kq * 4 + 1][r] = v.y;
            xs[kq * 4 + 2][r] = v.z; xs[kq * 4 + 3][r] = v.w;
        }
#pragma unroll
        for (int i = 0; i < 4; ++i) {
            int f = tid + i * 256;
            int kr = f >> 5;
            int c4 = f & 31;
            *reinterpret_cast<float4*>(&ws[kr][c4 * 4]) =
                *reinterpret_cast<const float4*>(W + (size_t)(kc + kr) * HDIM + c4 * 4);
        }
        __syncthreads();
#pragma unroll
        for (int k = 0; k < 32; ++k) {
            float4 xa = *reinterpret_cast<const float4*>(&xs[k][ty * 8]);
            float4 xb = *reinterpret_cast<const float4*>(&xs[k][ty * 8 + 4]);
            float4 w  = *reinterpret_cast<const float4*>(&ws[k][tx * 4]);
            const float xr[8] = {xa.x, xa.y, xa.z, xa.w, xb.x, xb.y, xb.z, xb.w};
            const float wc[4] = {w.x, w.y, w.z, w.w};
#pragma unroll
            for (int r = 0; r < 8; ++r)
#pragma unroll
                for (int c = 0; c < 4; ++c) acc[r][c] += xr[r] * wc[c];
        }
        __syncthreads();
    }
    float4 bb = make_float4(0.f, 0.f, 0.f, 0.f);
    if (BIAS) bb = *reinterpret_cast<const float4*>(b + tx * 4);
#pragma unroll
    for (int r = 0; r < 8; ++r) {
        int n = n0 + ty * 8 + r;
        if (n >= N) continue;
        *reinterpret_cast<float4*>(out + (size_t)n * HDIM + tx * 4) =
            make_float4(acc[r][0] + bb.x, acc[r][1] + bb.y,
                        acc[r][2] + bb.z, acc[r][3] + bb.w);
    }
}

// ---------------- 32-dim input gather: Y[c] = dinv[c]*X[c] + sum nrm*X[r] ----------------
__global__ __launch_bounds__(256) void gather_x_k(const int* __restrict__ row_ptr,
                                                  const int2* __restrict__ csr,
                                                  const float* __restrict__ dinv,
                                                  const float* __restrict__ X,
                                                  float* __restrict__ Y, int N) {
    int idx = blockIdx.x * 256 + threadIdx.x;   // per (node, octant)
    int c = idx >> 3;
    if (c >= N) return;
    int hq = idx & 7;
    int j0 = row_ptr[c], j1 = row_ptr[c + 1];
    float di = dinv[c];
    float4 xc = *reinterpret_cast<const float4*>(X + (size_t)c * 32 + hq * 4);
    float4 acc = make_float4(di * xc.x, di * xc.y, di * xc.z, di * xc.w);
    int j = j0;
    for (; j + 3 < j1; j += 4) {
        int2 e0 = csr[j], e1 = csr[j + 1], e2 = csr[j + 2], e3 = csr[j + 3];
        float4 v0 = *reinterpret_cast<const float4*>(X + (size_t)e0.x * 32 + hq * 4);
        float4 v1 = *reinterpret_cast<const float4*>(X + (size_t)e1.x * 32 + hq * 4);
        float4 v2 = *reinterpret_cast<const float4*>(X + (size_t)e2.x * 32 + hq * 4);
        float4 v3 = *reinterpret_cast<const float4*>(X + (size_t)e3.x * 32 + hq * 4);
        float n0 = __int_as_float(e0.y), n1 = __int_as_float(e1.y);
        float n2 = __int_as_float(e2.y), n3 = __int_as_float(e3.y);
        acc.x += n0 * v0.x + n1 * v1.x + n2 * v2.x + n3 * v3.x;
        acc.y += n0 * v0.y + n1 * v1.y + n2 * v2.y + n3 * v3.y;
        acc.z += n0 * v0.z + n1 * v1.z + n2 * v2.z + n3 * v3.z;
        acc.w += n0 * v0.w + n1 * v1.w + n2 * v2.w + n3 * v3.w;
    }
    for (; j < j1; ++j) {
        int2 en = csr[j];
        float nrm = __int_as_float(en.y);
        float4 v = *reinterpret_cast<const float4*>(X + (size_t)en.x * 32 + hq * 4);
        acc.x += nrm * v.x; acc.y += nrm * v.y;
        acc.z += nrm * v.z; acc.w += nrm * v.w;
    }
    *reinterpret_cast<float4*>(Y + (size_t)c * 32 + hq * 4) = acc;
}

// ---------------- 128-dim gather: out[c] = dinv[c]*xw[c] + b + sum nrm*xw[r] ----------------
__global__ __launch_bounds__(256) void gather_k(const int* __restrict__ row_ptr,
                                                const int2* __restrict__ csr,
                                                const float* __restrict__ dinv,
                                                const float* __restrict__ b,
                                                const float* __restrict__ xw,
                                                float* __restrict__ out, int N) {
    int idx = blockIdx.x * 256 + threadIdx.x;   // per (node, h-quad)
    int c = idx >> 5;
    if (c >= N) return;
    int hq = idx & 31;
    int j0 = row_ptr[c], j1 = row_ptr[c + 1];
    float4 xc = *reinterpret_cast<const float4*>(xw + (size_t)c * HDIM + hq * 4);
    float di = dinv[c];
    float4 bb = *reinterpret_cast<const float4*>(b + hq * 4);
    float4 acc = make_float4(di * xc.x + bb.x, di * xc.y + bb.y,
                             di * xc.z + bb.z, di * xc.w + bb.w);
    int j = j0;
    for (; j + 3 < j1; j += 4) {
        int2 e0 = csr[j], e1 = csr[j + 1], e2 = csr[j + 2], e3 = csr[j + 3];
        float4 v0 = *reinterpret_cast<const float4*>(xw + (size_t)e0.x * HDIM + hq * 4);
        float4 v1 = *reinterpret_cast<const float4*>(xw + (size_t)e1.x * HDIM + hq * 4);
        float4 v2 = *reinterpret_cast<const float4*>(xw + (size_t)e2.x * HDIM + hq * 4);
        float4 v3 = *reinterpret_cast<const float4*>(xw + (size_t)e3.x * HDIM + hq * 4);
        float n0 = __int_as_float(e0.y), n1 = __int_as_float(e1.y);
        float n2 = __int_as_float(e2.y), n3 = __int_as_float(e3.y);
        acc.x += n0 * v0.x + n1 * v1.x + n2 * v2.x + n3 * v3.x;
        acc.y += n0 * v0.y + n1 * v1.y + n2 * v2.y + n3 * v3.y;
        acc.z += n0 * v0.z + n1 * v1.z + n2 * v2.z + n3 * v3.z;
        acc.w += n0 * v0.w + n1 * v1.w + n2 * v2.w + n3 * v3.w;
    }
    for (; j < j1; ++j) {
        int2 en = csr[j];
        float nrm = __int_as_float(en.y);
        float4 v = *reinterpret_cast<const float4*>(xw + (size_t)en.x * HDIM + hq * 4);
        acc.x += nrm * v.x; acc.y += nrm * v.y;
        acc.z += nrm * v.z; acc.w += nrm * v.w;
    }
    *reinterpret_cast<float4*>(out + (size_t)c * HDIM + hq * 4) = acc;
}

// ---------------- graph start offsets (batch is sorted) ----------------
__global__ __launch_bounds__(256) void gstart_k(const int* __restrict__ batch,
                                                int* __restrict__ start, int N, int G) {
    int n = blockIdx.x * 256 + threadIdx.x;
    if (n > N) return;
    if (n < N) {
        int b = batch[n];
        int prev = (n == 0) ? -1 : batch[n - 1];
        for (int g = prev + 1; g <= b; ++g) start[g] = n;
    } else {
        int prev = batch[N - 1];
        for (int g = prev + 1; g <= G; ++g) start[g] = N;
    }
}

// ---------------- fused mean-pool + final linear ----------------
__global__ __launch_bounds__(256) void final_pool_k(const float* __restrict__ h,
                                                    const int* __restrict__ start,
                                                    const float* __restrict__ Wlin,
                                                    const float* __restrict__ blin,
                                                    float* __restrict__ out, int G) {
    int g = blockIdx.x * 4 + (threadIdx.x >> 6);
    int lane = threadIdx.x & 63;
    if (g >= G) return;
    int s = start[g], e = start[g + 1];
    float w0 = Wlin[lane], w1 = Wlin[lane + 64];
    float acc = 0.f;
    for (int n = s; n < e; ++n) {
        const float* p = h + (size_t)n * HDIM;
        acc += p[lane] * w0 + p[lane + 64] * w1;
    }
#pragma unroll
    for (int off = 32; off > 0; off >>= 1) acc += __shfl_down(acc, off);
    if (lane == 0) out[g] = acc / fmaxf((float)(e - s), 1.0f) + blin[0];
}

extern "C" void kernel_launch(void* const* d_in, const int* in_sizes, int n_in,
                              void* d_out, int out_size, void* d_ws, size_t ws_size,
                              hipStream_t stream) {
    const float* x    = (const float*)d_in[0];
    const float* W1   = (const float*)d_in[1];
    const float* b1   = (const float*)d_in[2];
    const float* W2   = (const float*)d_in[3];
    const float* b2   = (const float*)d_in[4];
    const float* W3   = (const float*)d_in[5];
    const float* b3   = (const float*)d_in[6];
    const float* Wlin = (const float*)d_in[7];
    const float* blin = (const float*)d_in[8];
    const int* ei     = (const int*)d_in[9];
    const int* batch  = (const int*)d_in[10];

    const int N = in_sizes[10];
    const int E = in_sizes[9] / 2;
    const int G = out_size;
    const size_t NH = (size_t)N * HDIM;
    const int NB = (N + 255) / 256;               // scan blocks (<=512)

    const int* row = ei;
    const int* col = ei + E;

    // workspace layout (csr first for 8B alignment)
    int2* csr     = (int2*)d_ws;                 // [E]
    float* xw     = (float*)(csr + E);           // [N,H]  (also holds Y[N,32] in layer 1)
    float* bufA   = xw + NH;                     // [N,H]
    float* dis    = bufA + NH;                   // [N]
    float* dinv   = dis + N;                     // [N]
    int* deg_i    = (int*)(dinv + N);            // [N]
    int* row_ptr  = deg_i + N;                   // [N+1]
    int* cursor   = row_ptr + N + 1;             // [N]
    int* gstart   = cursor + N;                  // [G+1]
    int* incl     = gstart + G + 1;              // [N]
    int* partial  = incl + N;                    // [NB]

    float* outf = (float*)d_out;

    // ---- CSR build ----
    hipMemsetAsync(deg_i, 0, (size_t)N * sizeof(int), stream);
    hipMemsetAsync(cursor, 0, (size_t)N * sizeof(int), stream);
    deg_hist_k<<<(E + 255) / 256, 256, 0, stream>>>(col, deg_i, E);
    deg_finish_k<<<(N + 255) / 256, 256, 0, stream>>>(deg_i, dis, dinv, N);
    scan1_k<<<NB, 256, 0, stream>>>(deg_i, incl, partial, N);
    scan2_k<<<1, 512, 0, stream>>>(partial, NB);
    scan3_k<<<NB, 256, 0, stream>>>(deg_i, incl, partial, row_ptr, N);
    csr_fill_k<<<(E + 255) / 256, 256, 0, stream>>>(row, col, dis, row_ptr, cursor, csr, E);
    gstart_k<<<(N + 256) / 256, 256, 0, stream>>>(batch, gstart, N, G);

    const int gemm_grid = (N + 63) / 64;
    const int gath_grid = (N * 32 + 255) / 256;

    // layer 1 (aggregate-first): Y = A_hat X  (32-dim gather), out1 = Y W1 + b1 -> bufA
    gather_x_k<<<(N * 8 + 255) / 256, 256, 0, stream>>>(row_ptr, csr, dinv, x, xw, N);
    gemm_gcn<32, false, true><<<gemm_grid, 256, 0, stream>>>(xw, W1, b1, bufA, N);
    // layer 2: relu(bufA) W2 -> xw ; gather(+b2) -> bufA
    gemm_gcn<128, true, false><<<gemm_grid, 256, 0, stream>>>(bufA, W2, nullptr, xw, N);
    gather_k<<<gath_grid, 256, 0, stream>>>(row_ptr, csr, dinv, b2, xw, bufA, N);
    // layer 3: relu(bufA) W3 -> xw ; gather(+b3) -> bufA
    gemm_gcn<128, true, false><<<gemm_grid, 256, 0, stream>>>(bufA, W3, nullptr, xw, N);
    gather_k<<<gath_grid, 256, 0, stream>>>(row_ptr, csr, dinv, b3, xw, bufA, N);

    // fused mean-pool + linear
    final_pool_k<<<(G + 3) / 4, 256, 0, stream>>>(bufA, gstart, Wlin, blin, outf, G);
}